// Round 1
// baseline (267.563 us; speedup 1.0000x reference)
//
#include <hip/hip_runtime.h>

// Sparsemax over last dim, rows of N=512 fp32.
// One 64-lane wave per row; 8 elements/lane held in registers.
// tau found by Michelot's algorithm (exact fixed point of the simplex
// projection) instead of sort+cumsum -> pure streaming kernel.

#define ROW_N 512
#define LANES 64
#define EPL 8  // elements per lane = 512/64

__global__ __launch_bounds__(256) void sparsemax_kernel(
    const float* __restrict__ x, float* __restrict__ out, int nrows) {
  const int lane = threadIdx.x & 63;
  const int wave = threadIdx.x >> 6;
  const int row = blockIdx.x * 4 + wave;
  if (row >= nrows) return;

  const float4* xr = (const float4*)(x + (size_t)row * ROW_N);
  float4* outr = (float4*)(out + (size_t)row * ROW_N);

  // Coalesced load: lane i grabs float4 at i and i+64 (full 2KiB row).
  float4 a = xr[lane];
  float4 b = xr[lane + LANES];
  float z[EPL] = {a.x, a.y, a.z, a.w, b.x, b.y, b.z, b.w};

  // Row max (shift for stability, matches reference; doesn't change tau).
  float m = z[0];
#pragma unroll
  for (int i = 1; i < EPL; ++i) m = fmaxf(m, z[i]);
#pragma unroll
  for (int off = 32; off >= 1; off >>= 1) m = fmaxf(m, __shfl_xor(m, off, 64));
#pragma unroll
  for (int i = 0; i < EPL; ++i) z[i] -= m;

  // Initial tau with full support (double accumulation: summation-order
  // differences vs the fp32 np reference stay far below threshold).
  double s = 0.0;
#pragma unroll
  for (int i = 0; i < EPL; ++i) s += (double)z[i];
#pragma unroll
  for (int off = 32; off >= 1; off >>= 1) s += __shfl_xor(s, off, 64);
  double tau = (s - 1.0) / (double)ROW_N;

  // Michelot: support shrinks monotonically; same count => same set => done.
  int prev_cnt = ROW_N;
  for (int iter = 0; iter < 64; ++iter) {
    const float tf = (float)tau;
    double ls = 0.0;
    int lc = 0;
#pragma unroll
    for (int i = 0; i < EPL; ++i) {
      bool g = z[i] > tf;
      ls += g ? (double)z[i] : 0.0;
      lc += g ? 1 : 0;
    }
#pragma unroll
    for (int off = 32; off >= 1; off >>= 1) {
      ls += __shfl_xor(ls, off, 64);
      lc += __shfl_xor(lc, off, 64);
    }
    tau = (ls - 1.0) / (double)lc;
    if (lc == prev_cnt) break;  // support stable -> tau is the fixed point
    prev_cnt = lc;
  }

  const float tf = (float)tau;
  float4 oa = {fmaxf(z[0] - tf, 0.0f), fmaxf(z[1] - tf, 0.0f),
               fmaxf(z[2] - tf, 0.0f), fmaxf(z[3] - tf, 0.0f)};
  float4 ob = {fmaxf(z[4] - tf, 0.0f), fmaxf(z[5] - tf, 0.0f),
               fmaxf(z[6] - tf, 0.0f), fmaxf(z[7] - tf, 0.0f)};
  outr[lane] = oa;
  outr[lane + LANES] = ob;
}

extern "C" void kernel_launch(void* const* d_in, const int* in_sizes, int n_in,
                              void* d_out, int out_size, void* d_ws,
                              size_t ws_size, hipStream_t stream) {
  const float* x = (const float*)d_in[0];
  float* out = (float*)d_out;
  const int nrows = in_sizes[0] / ROW_N;
  const int blocks = (nrows + 3) / 4;
  sparsemax_kernel<<<blocks, 256, 0, stream>>>(x, out, nrows);
}

// Round 2
// 226.356 us; speedup vs baseline: 1.1820x; 1.1820x over previous
//
#include <hip/hip_runtime.h>

// Sparsemax over last dim, rows of N=512 fp32.
// One 64-lane wave per row; 8 elements/lane in registers.
// tau via Michelot fixed-point iteration; all cross-lane reductions are
// DPP-based (pure VALU, no ds_swizzle latency), all arithmetic fp32.

#define ROW_N 512
#define LANES 64
#define EPL 8  // elements per lane

// One DPP step: v = v + dpp_move(v). bound_ctrl=1 -> out-of-bounds lanes read 0
// (additive identity). Masked-off rows get `old`=0, also identity for add.
#define DPP_ADD_STEP(v, ctrl, rmask)                                        \
  v += __int_as_float(__builtin_amdgcn_update_dpp(                          \
      0, __float_as_int(v), ctrl, rmask, 0xf, true))

// Full-wave (64-lane) sum; returns the total, uniform across the wave.
__device__ inline float wave_sum64(float v) {
  DPP_ADD_STEP(v, 0x111, 0xf);  // row_shr:1
  DPP_ADD_STEP(v, 0x112, 0xf);  // row_shr:2
  DPP_ADD_STEP(v, 0x114, 0xf);  // row_shr:4
  DPP_ADD_STEP(v, 0x118, 0xf);  // row_shr:8  -> lane15 of each row = row sum
  DPP_ADD_STEP(v, 0x142, 0xa);  // row_bcast:15 -> lanes 31, 63 accumulate
  DPP_ADD_STEP(v, 0x143, 0xc);  // row_bcast:31 -> lane 63 = wave total
  return __int_as_float(__builtin_amdgcn_readlane(__float_as_int(v), 63));
}

// Full-wave max: identity-old variant (invalid/masked lanes contribute v).
#define DPP_MAX_STEP(v, ctrl, rmask)                                        \
  v = fmaxf(v, __int_as_float(__builtin_amdgcn_update_dpp(                  \
             __float_as_int(v), __float_as_int(v), ctrl, rmask, 0xf, false)))

__device__ inline float wave_max64(float v) {
  DPP_MAX_STEP(v, 0x111, 0xf);
  DPP_MAX_STEP(v, 0x112, 0xf);
  DPP_MAX_STEP(v, 0x114, 0xf);
  DPP_MAX_STEP(v, 0x118, 0xf);
  DPP_MAX_STEP(v, 0x142, 0xa);
  DPP_MAX_STEP(v, 0x143, 0xc);
  return __int_as_float(__builtin_amdgcn_readlane(__float_as_int(v), 63));
}

__global__ __launch_bounds__(256) void sparsemax_kernel(
    const float* __restrict__ x, float* __restrict__ out, int nrows) {
  const int lane = threadIdx.x & 63;
  const int wave = threadIdx.x >> 6;
  const int row = blockIdx.x * 4 + wave;
  if (row >= nrows) return;

  const float4* xr = (const float4*)(x + (size_t)row * ROW_N);
  float4* outr = (float4*)(out + (size_t)row * ROW_N);

  float4 a = xr[lane];
  float4 b = xr[lane + LANES];
  float z[EPL] = {a.x, a.y, a.z, a.w, b.x, b.y, b.z, b.w};

  // Row max (stability shift, matches reference).
  float m = z[0];
#pragma unroll
  for (int i = 1; i < EPL; ++i) m = fmaxf(m, z[i]);
  m = wave_max64(m);
#pragma unroll
  for (int i = 0; i < EPL; ++i) z[i] -= m;

  // Initial tau with full support.
  float s = 0.0f;
#pragma unroll
  for (int i = 0; i < EPL; ++i) s += z[i];
  s = wave_sum64(s);
  float tau = (s - 1.0f) * (1.0f / (float)ROW_N);

  // Michelot: support shrinks monotonically; same count => same set => done.
  float prev_cnt = (float)ROW_N;
  for (int iter = 0; iter < 64; ++iter) {
    float ls = 0.0f, lc = 0.0f;
#pragma unroll
    for (int i = 0; i < EPL; ++i) {
      bool g = z[i] > tau;
      ls += g ? z[i] : 0.0f;
      lc += g ? 1.0f : 0.0f;
    }
    ls = wave_sum64(ls);
    lc = wave_sum64(lc);  // exact: integer-valued, <= 512
    tau = (ls - 1.0f) / lc;
    if (lc == prev_cnt) break;  // support stable -> tau is the fixed point
    prev_cnt = lc;
  }

  float4 oa = {fmaxf(z[0] - tau, 0.0f), fmaxf(z[1] - tau, 0.0f),
               fmaxf(z[2] - tau, 0.0f), fmaxf(z[3] - tau, 0.0f)};
  float4 ob = {fmaxf(z[4] - tau, 0.0f), fmaxf(z[5] - tau, 0.0f),
               fmaxf(z[6] - tau, 0.0f), fmaxf(z[7] - tau, 0.0f)};
  outr[lane] = oa;
  outr[lane + LANES] = ob;
}

extern "C" void kernel_launch(void* const* d_in, const int* in_sizes, int n_in,
                              void* d_out, int out_size, void* d_ws,
                              size_t ws_size, hipStream_t stream) {
  const float* x = (const float*)d_in[0];
  float* out = (float*)d_out;
  const int nrows = in_sizes[0] / ROW_N;
  const int blocks = (nrows + 3) / 4;
  sparsemax_kernel<<<blocks, 256, 0, stream>>>(x, out, nrows);
}